// Round 4
// baseline (578.207 us; speedup 1.0000x reference)
//
#include <hip/hip_runtime.h>
#include <cstdint>

#define HH 76
#define WW 128
#define AA 9
#define HWH (HH * WW)          // 9728
#define KK (HWH * AA)          // 87552
#define NSEL 6000
#define NCH 94                 // ceil(6000/64)
#define NPAD (NCH * 64)        // 6016
#define NOUT 1000
#define CAP 8192
#define NMS_T 0.7
#define NBLK 256
#define NTHR 1024
#define NTRI (NCH * (NCH + 1) / 2)  // 4465 upper-tri tiles

// ---- workspace layout (bytes) ----
#define WS_HIST 0              // u32[65536]
#define WS_COUNTER 262144      // u32
#define WS_BINB 262148         // u32
#define WS_BAR 262152          // u32[16] grid-barrier counters
#define WS_SELKEYS 262224      // u64[8192]
#define WS_BOXES 327760        // float4[6016]
#define WS_MASK 424016         // u64 maskT[NCH][NPAD] (diag words hold TRANSPOSED diag)
#define WS_ZERO_BYTES 262216   // prefix zeroed every replay (hist+counter+binB+bar)

// base anchors from generate_anchors() (numpy fp64, exact small values)
__device__ __constant__ float c_ax1[9] = {-84.f, -176.f, -360.f, -56.f, -120.f, -248.f, -36.f, -80.f, -168.f};
__device__ __constant__ float c_ay1[9] = {-40.f, -88.f, -184.f, -56.f, -120.f, -248.f, -80.f, -168.f, -344.f};
__device__ __constant__ float c_ax2[9] = {99.f, 191.f, 375.f, 71.f, 135.f, 263.f, 51.f, 95.f, 183.f};
__device__ __constant__ float c_ay2[9] = {55.f, 103.f, 199.f, 71.f, 135.f, 263.f, 95.f, 183.f, 359.f};

__device__ __forceinline__ unsigned score_key(float s) {
    unsigned u = __float_as_uint(s);
    return (u & 0x80000000u) ? ~u : (u | 0x80000000u);
}

// 64-lane OR-reduce via DPP (result valid in lane 63). OR idempotent -> bcast quirks harmless.
__device__ __forceinline__ unsigned wave_or32(unsigned v) {
    v |= (unsigned)__builtin_amdgcn_update_dpp(0, (int)v, 0x111, 0xf, 0xf, true);
    v |= (unsigned)__builtin_amdgcn_update_dpp(0, (int)v, 0x112, 0xf, 0xf, true);
    v |= (unsigned)__builtin_amdgcn_update_dpp(0, (int)v, 0x114, 0xf, 0xf, true);
    v |= (unsigned)__builtin_amdgcn_update_dpp(0, (int)v, 0x118, 0xf, 0xf, true);
    v |= (unsigned)__builtin_amdgcn_update_dpp(0, (int)v, 0x142, 0xf, 0xf, true);
    v |= (unsigned)__builtin_amdgcn_update_dpp(0, (int)v, 0x143, 0xf, 0xf, true);
    return v;
}

// device-scope grid barrier (all NBLK blocks co-resident by construction)
__device__ __forceinline__ void gsync(unsigned* bar, int phase) {
    __syncthreads();
    if (threadIdx.x == 0) {
        __threadfence();  // agent release: writeback this XCD's L2
        __hip_atomic_fetch_add(&bar[phase], 1u, __ATOMIC_ACQ_REL, __HIP_MEMORY_SCOPE_AGENT);
        while (__hip_atomic_load(&bar[phase], __ATOMIC_ACQUIRE, __HIP_MEMORY_SCOPE_AGENT) < (unsigned)NBLK) {
            __builtin_amdgcn_s_sleep(2);
        }
        __threadfence();  // agent acquire: invalidate stale L1/L2
    }
    __syncthreads();
}

__global__ __launch_bounds__(NTHR, 4) void k_fused(const float* scores, const float* bbox,
                                                   const float* im_info, char* ws,
                                                   float4* out) {
    __shared__ __align__(16) unsigned long long shm64[CAP];  // 64 KiB, phase-unioned

    unsigned* hist = (unsigned*)(ws + WS_HIST);
    unsigned* counterG = (unsigned*)(ws + WS_COUNTER);
    unsigned* binB = (unsigned*)(ws + WS_BINB);
    unsigned* bar = (unsigned*)(ws + WS_BAR);
    unsigned long long* selKeys = (unsigned long long*)(ws + WS_SELKEYS);
    float4* boxes = (float4*)(ws + WS_BOXES);
    unsigned long long* maskT = (unsigned long long*)(ws + WS_MASK);

    const int t = threadIdx.x;
    const int bid = blockIdx.x;
    const int gid = bid * NTHR + t;
    const int wave = t >> 6, lane = t & 63;

    // ================= P0: score-key histogram =================
    if (gid < KK) {
        int a = gid % AA;
        int hw = gid / AA;
        int h = hw >> 7, w = hw & 127;
        float s = scores[(AA + a) * HWH + h * WW + w];
        atomicAdd(&hist[score_key(s) >> 16], 1u);
    }
    gsync(bar, 0);

    // ================= P1: find threshold bin (block 0) =================
    if (bid == 0) {
        unsigned* seg = (unsigned*)shm64;
        unsigned local[64];
        unsigned ssum = 0;
#pragma unroll
        for (int k = 0; k < 64; ++k) { local[k] = hist[t * 64 + k]; ssum += local[k]; }
        seg[t] = ssum;
        __syncthreads();
        for (int off = 1; off < NTHR; off <<= 1) {
            unsigned v = seg[t];
            unsigned add = (t + off < NTHR) ? seg[t + off] : 0u;
            __syncthreads();
            seg[t] = v + add;
            __syncthreads();
        }
        unsigned above = (t + 1 < NTHR) ? seg[t + 1] : 0u;
        if (above < NSEL && above + ssum >= NSEL) {
            unsigned acc = above;
#pragma unroll
            for (int b = 63; b >= 0; --b) {
                acc += local[b];
                if (acc >= NSEL) { *binB = (unsigned)(t * 64 + b); break; }
            }
        }
    }
    gsync(bar, 1);

    // ================= P2: gather candidates =================
    if (gid < KK) {
        int a = gid % AA;
        int hw = gid / AA;
        int h = hw >> 7, w = hw & 127;
        float s = scores[(AA + a) * HWH + h * WW + w];
        unsigned key = score_key(s);
        if ((key >> 16) >= *binB) {
            unsigned pos = atomicAdd(counterG, 1u);
            if (pos < CAP)
                selKeys[pos] = ((unsigned long long)key << 32) | (unsigned)(~(unsigned)gid);
        }
    }
    gsync(bar, 2);

    // ================= P3: bitonic sort + decode (block 0) =================
    if (bid == 0) {
        unsigned long long* sk = shm64;
        unsigned cnt = *counterG;
        if (cnt > CAP) cnt = CAP;
        for (int p = t; p < CAP; p += NTHR) sk[p] = (p < (int)cnt) ? selKeys[p] : 0ull;
        __syncthreads();
        for (unsigned size = 2; size <= CAP; size <<= 1) {
            for (unsigned stride = size >> 1; stride > 0; stride >>= 1) {
                for (unsigned p = (unsigned)t; p < CAP / 2; p += NTHR) {
                    unsigned i = 2u * p - (p & (stride - 1u));
                    unsigned j = i + stride;
                    bool up = (i & size) != 0;
                    unsigned long long a = sk[i], b = sk[j];
                    bool doswap = up ? (a > b) : (a < b);
                    if (doswap) { sk[i] = b; sk[j] = a; }
                }
                __syncthreads();
            }
        }
        // decode+clip top-6000 (fp64, store fp32)
        double xmax = (double)im_info[1] - 1.0, ymax = (double)im_info[0] - 1.0;
        for (int r = t; r < NSEL; r += NTHR) {
            unsigned i = ~(unsigned)(sk[r] & 0xFFFFFFFFull);
            int a = (int)(i % AA);
            int hw = (int)(i / AA);
            int h = hw >> 7, w = hw & 127;
            double sx = 16.0 * w, sy = 16.0 * h;
            double ax1 = (double)c_ax1[a] + sx, ay1 = (double)c_ay1[a] + sy;
            double ax2 = (double)c_ax2[a] + sx, ay2 = (double)c_ay2[a] + sy;
            double aw = ax2 - ax1 + 1.0, ah = ay2 - ay1 + 1.0;
            double acx = ax1 + 0.5 * aw, acy = ay1 + 0.5 * ah;
            int base = h * WW + w;
            double d0 = (double)bbox[(4 * a + 0) * HWH + base];
            double d1 = (double)bbox[(4 * a + 1) * HWH + base];
            double d2 = (double)bbox[(4 * a + 2) * HWH + base];
            double d3 = (double)bbox[(4 * a + 3) * HWH + base];
            double pcx = d0 * aw + acx, pcy = d1 * ah + acy;
            double pw = exp(d2) * aw, ph = exp(d3) * ah;
            double x1 = fmin(fmax(pcx - 0.5 * pw, 0.0), xmax);
            double y1 = fmin(fmax(pcy - 0.5 * ph, 0.0), ymax);
            double x2 = fmin(fmax(pcx + 0.5 * pw, 0.0), xmax);
            double y2 = fmin(fmax(pcy + 0.5 * ph, 0.0), ymax);
            boxes[r] = make_float4((float)x1, (float)y1, (float)x2, (float)y2);
        }
    }
    gsync(bar, 3);

    // ================= P4: suppression bitmask (wave-per-tile) =================
    {
        float4* cb = (float4*)shm64;  // [16][64]
        int slot = bid * 16 + wave;
        for (int L = slot; L < NTRI; L += NBLK * 16) {
            int rc = 0, rem = L;
            while (rem >= NCH - rc) { rem -= NCH - rc; rc++; }
            int cc = rc + rem;
            cb[wave * 64 + lane] = boxes[cc * 64 + lane];
            int gi = rc * 64 + lane;
            unsigned long long bits = 0ull;
            if (gi < NSEL) {
                float4 rb = boxes[gi];
                double rx1 = rb.x, ry1 = rb.y, rx2 = rb.z, ry2 = rb.w;
                double rarea = (rx2 - rx1 + 1.0) * (ry2 - ry1 + 1.0);
                for (int j = 0; j < 64; ++j) {
                    int gj = cc * 64 + j;
                    float4 c = cb[wave * 64 + j];
                    double iw = fmin(rx2, (double)c.z) - fmax(rx1, (double)c.x) + 1.0;
                    double ih = fmin(ry2, (double)c.w) - fmax(ry1, (double)c.y) + 1.0;
                    if (gj > gi && gj < NSEL && iw > 0.0 && ih > 0.0) {
                        double inter = iw * ih;
                        double carea = ((double)c.z - (double)c.x + 1.0) * ((double)c.w - (double)c.y + 1.0);
                        double uni = rarea + carea - inter;
                        if (inter > NMS_T * uni) bits |= (1ull << j);
                    }
                }
            }
            if (rc != cc) {
                if (gi < NSEL) maskT[(size_t)cc * NPAD + gi] = bits;
            } else {
                // diag: store TRANSPOSED block (col-view) into the diag words
                unsigned long long myword = 0ull;
                for (int j = 0; j < 64; ++j) {
                    unsigned long long bal = __ballot((int)((bits >> j) & 1ull));
                    if (lane == j) myword = bal;
                }
                maskT[(size_t)cc * NPAD + cc * 64 + lane] = myword;
            }
        }
    }
    gsync(bar, 4);

    // ================= P5: greedy NMS + compaction (block 0) =================
    if (bid == 0) {
        unsigned long long* removed = shm64;                 // [NCH]
        unsigned long long* aliveSh = shm64 + 96;            // [2]
        int* cstop = (int*)(shm64 + 98);
        unsigned* scanBuf = (unsigned*)(shm64 + 128);        // [1024]

        if (t < NCH) removed[t] = (t == NCH - 1) ? 0xFFFF000000000000ull : 0ull;
        if (t == 0) *cstop = -1;
        __syncthreads();

        unsigned long long colA = 0, wAr = 0, colB = 0, wBr = 0;  // wave0 regs
        unsigned long long mA[7], mB[7];                           // waves 1-15
        if (wave == 0) {
            colA = maskT[(size_t)0 * NPAD + 0 * 64 + lane];
            wAr = maskT[(size_t)1 * NPAD + 0 * 64 + lane];
            colB = maskT[(size_t)1 * NPAD + 1 * 64 + lane];
            wBr = maskT[(size_t)2 * NPAD + 1 * 64 + lane];
        } else {
#pragma unroll
            for (int q = 0; q < 7; ++q) {
                int w = 2 + (wave - 1) + 15 * q;
                mA[q] = (w < NCH) ? maskT[(size_t)w * NPAD + 0 * 64 + lane] : 0ull;
            }
#pragma unroll
            for (int q = 0; q < 7; ++q) {
                int w = 3 + (wave - 1) + 15 * q;
                mB[q] = (w < NCH) ? maskT[(size_t)w * NPAD + 1 * 64 + lane] : 0ull;
            }
        }
        unsigned keptTot = 0;

        for (int c = 0; c < NCH; c += 2) {
            // ---- even chunk c ----
            if (wave == 0) {
                unsigned long long rem = removed[c];
                unsigned alo = __builtin_amdgcn_readfirstlane((unsigned)(~rem));
                unsigned ahi = __builtin_amdgcn_readfirstlane((unsigned)((~rem) >> 32));
                unsigned long long alive = ((unsigned long long)ahi << 32) | alo;
                unsigned long long rest = alive;
                while (rest) {
                    int i = __ffsll((long long)rest) - 1;
                    unsigned long long sup = __ballot((int)((colA >> i) & 1ull));
                    alive &= ~sup;
                    rest &= ~sup;
                    rest &= rest - 1ull;
                }
                keptTot += (unsigned)__popcll(alive);
                if (lane == 0) {
                    removed[c] = ~alive;
                    aliveSh[0] = alive;
                    if (keptTot >= NOUT) *cstop = c;
                }
                if (c + 1 < NCH) {
                    unsigned long long sel = 0ull - ((alive >> lane) & 1ull);
                    unsigned long long v = wAr & sel;
                    unsigned lo = wave_or32((unsigned)v);
                    unsigned hi = wave_or32((unsigned)(v >> 32));
                    if (lane == 63) atomicOr(&removed[c + 1], ((unsigned long long)hi << 32) | lo);
                }
                if (c + 2 < NCH) {
                    colA = maskT[(size_t)(c + 2) * NPAD + (c + 2) * 64 + lane];
                    wAr = (c + 3 < NCH) ? maskT[(size_t)(c + 3) * NPAD + (c + 2) * 64 + lane] : 0ull;
                }
            }
            __syncthreads();  // B1
            if (*cstop >= 0) break;
            if (wave > 0) {
                unsigned long long alive = aliveSh[0];
                unsigned long long sel = 0ull - ((alive >> lane) & 1ull);
#pragma unroll
                for (int q = 0; q < 7; ++q) {
                    int w = c + 2 + (wave - 1) + 15 * q;
                    if (w < NCH) {
                        unsigned long long v = mA[q] & sel;
                        unsigned lo = wave_or32((unsigned)v);
                        unsigned hi = wave_or32((unsigned)(v >> 32));
                        if (lane == 63) atomicOr(&removed[w], ((unsigned long long)hi << 32) | lo);
                    }
                }
#pragma unroll
                for (int q = 0; q < 7; ++q) {
                    int w = (c + 2) + 2 + (wave - 1) + 15 * q;
                    mA[q] = (w < NCH) ? maskT[(size_t)w * NPAD + (c + 2) * 64 + lane] : 0ull;
                }
            }
            // ---- odd chunk c+1 (wave0, concurrent with the OR above) ----
            if (wave == 0) {
                unsigned long long rem = removed[c + 1];
                unsigned alo = __builtin_amdgcn_readfirstlane((unsigned)(~rem));
                unsigned ahi = __builtin_amdgcn_readfirstlane((unsigned)((~rem) >> 32));
                unsigned long long alive = ((unsigned long long)ahi << 32) | alo;
                unsigned long long rest = alive;
                while (rest) {
                    int i = __ffsll((long long)rest) - 1;
                    unsigned long long sup = __ballot((int)((colB >> i) & 1ull));
                    alive &= ~sup;
                    rest &= ~sup;
                    rest &= rest - 1ull;
                }
                keptTot += (unsigned)__popcll(alive);
                if (lane == 0) {
                    removed[c + 1] = ~alive;
                    aliveSh[1] = alive;
                    if (keptTot >= NOUT) *cstop = c + 1;
                }
                if (c + 2 < NCH) {
                    unsigned long long sel = 0ull - ((alive >> lane) & 1ull);
                    unsigned long long v = wBr & sel;
                    unsigned lo = wave_or32((unsigned)v);
                    unsigned hi = wave_or32((unsigned)(v >> 32));
                    if (lane == 63) atomicOr(&removed[c + 2], ((unsigned long long)hi << 32) | lo);
                }
                if (c + 3 < NCH) {
                    colB = maskT[(size_t)(c + 3) * NPAD + (c + 3) * 64 + lane];
                    wBr = (c + 4 < NCH) ? maskT[(size_t)(c + 4) * NPAD + (c + 3) * 64 + lane] : 0ull;
                }
            }
            __syncthreads();  // B2
            if (*cstop >= 0) break;
            if (wave > 0) {
                unsigned long long alive = aliveSh[1];
                unsigned long long sel = 0ull - ((alive >> lane) & 1ull);
#pragma unroll
                for (int q = 0; q < 7; ++q) {
                    int w = c + 3 + (wave - 1) + 15 * q;
                    if (w < NCH) {
                        unsigned long long v = mB[q] & sel;
                        unsigned lo = wave_or32((unsigned)v);
                        unsigned hi = wave_or32((unsigned)(v >> 32));
                        if (lane == 63) atomicOr(&removed[w], ((unsigned long long)hi << 32) | lo);
                    }
                }
#pragma unroll
                for (int q = 0; q < 7; ++q) {
                    int w = (c + 3) + 2 + (wave - 1) + 15 * q;
                    mB[q] = (w < NCH) ? maskT[(size_t)w * NPAD + (c + 3) * 64 + lane] : 0ull;
                }
            }
        }
        __syncthreads();

        // stable compaction: kept (index asc) then suppressed (index asc), first 1000
        int base = t * 6;
        unsigned cnt = 0, keepbits = 0;
        for (int q = 0; q < 6; ++q) {
            int i = base + q;
            if (i < NSEL) {
                bool kp = !((removed[i >> 6] >> (i & 63)) & 1ull);
                if (kp) { cnt++; keepbits |= (1u << q); }
            }
        }
        scanBuf[t] = cnt;
        __syncthreads();
        for (int off = 1; off < NTHR; off <<= 1) {
            unsigned v = scanBuf[t];
            unsigned add = (t >= off) ? scanBuf[t - off] : 0u;
            __syncthreads();
            scanBuf[t] = v + add;
            __syncthreads();
        }
        unsigned incl = scanBuf[t];
        unsigned NK = scanBuf[NTHR - 1];
        unsigned kpos = incl - cnt;
        for (int q = 0; q < 6; ++q) {
            int i = base + q;
            if (i < NSEL) {
                bool kp = (keepbits >> q) & 1u;
                unsigned pos = kp ? kpos : (NK + (unsigned)i - kpos);
                if (kp) kpos++;
                if (pos < NOUT) out[pos] = boxes[i];
            }
        }
    }
}

extern "C" void kernel_launch(void* const* d_in, const int* in_sizes, int n_in,
                              void* d_out, int out_size, void* d_ws, size_t ws_size,
                              hipStream_t stream) {
    const float* scores = (const float*)d_in[0];
    const float* bbox = (const float*)d_in[1];
    const float* im_info = (const float*)d_in[2];
    char* ws = (char*)d_ws;
    float4* out = (float4*)d_out;

    hipMemsetAsync(ws, 0, WS_ZERO_BYTES, stream);
    k_fused<<<NBLK, NTHR, 0, stream>>>(scores, bbox, im_info, ws, out);
}

// Round 5
// 251.346 us; speedup vs baseline: 2.3004x; 2.3004x over previous
//
#include <hip/hip_runtime.h>
#include <cstdint>

#define HH 76
#define WW 128
#define AA 9
#define HWH (HH * WW)          // 9728
#define KK (HWH * AA)          // 87552
#define NSEL 6000
#define NCH 94                 // ceil(6000/64)
#define NPAD (NCH * 64)        // 6016
#define NOUT 1000
#define CAP 8192
#define NMS_T 0.7
#define NTRI (NCH * (NCH + 1) / 2)  // 4465 upper-tri tiles
#define MASK_BLOCKS 1117            // ceil(NTRI/4) wave-per-tile

// ---- workspace layout (bytes) ----
#define WS_HIST 0              // u32[65536]
#define WS_COUNTER 262144      // u32
#define WS_BINB 262148         // u32
#define WS_SELKEYS 262152      // u64[8192]
#define WS_BOXES 327696        // float4[6016] (16-aligned)
#define WS_MASK 423952         // u64 maskT[NCH][NPAD]; diag words hold TRANSPOSED diag
#define WS_ZERO_BYTES 262152   // hist+counter+binB zeroed every replay

// base anchors from generate_anchors() (numpy fp64, exact small values)
__device__ __constant__ float c_ax1[9] = {-84.f, -176.f, -360.f, -56.f, -120.f, -248.f, -36.f, -80.f, -168.f};
__device__ __constant__ float c_ay1[9] = {-40.f, -88.f, -184.f, -56.f, -120.f, -248.f, -80.f, -168.f, -344.f};
__device__ __constant__ float c_ax2[9] = {99.f, 191.f, 375.f, 71.f, 135.f, 263.f, 51.f, 95.f, 183.f};
__device__ __constant__ float c_ay2[9] = {55.f, 103.f, 199.f, 71.f, 135.f, 263.f, 95.f, 183.f, 359.f};

__device__ __forceinline__ unsigned score_key(float s) {
    unsigned u = __float_as_uint(s);
    return (u & 0x80000000u) ? ~u : (u | 0x80000000u);
}

// 64-lane OR-reduce via DPP (result valid in lane 63). OR idempotent -> bcast quirks harmless.
__device__ __forceinline__ unsigned wave_or32(unsigned v) {
    v |= (unsigned)__builtin_amdgcn_update_dpp(0, (int)v, 0x111, 0xf, 0xf, true);
    v |= (unsigned)__builtin_amdgcn_update_dpp(0, (int)v, 0x112, 0xf, 0xf, true);
    v |= (unsigned)__builtin_amdgcn_update_dpp(0, (int)v, 0x114, 0xf, 0xf, true);
    v |= (unsigned)__builtin_amdgcn_update_dpp(0, (int)v, 0x118, 0xf, 0xf, true);
    v |= (unsigned)__builtin_amdgcn_update_dpp(0, (int)v, 0x142, 0xf, 0xf, true);
    v |= (unsigned)__builtin_amdgcn_update_dpp(0, (int)v, 0x143, 0xf, 0xf, true);
    return v;
}

// 1) histogram over top-16 bits of orderable score key
__global__ void k_hist(const float* __restrict__ scores, unsigned* __restrict__ hist) {
    int i = blockIdx.x * blockDim.x + threadIdx.x;
    if (i >= KK) return;
    int a = i % AA;
    int hw = i / AA;
    int h = hw >> 7, w = hw & 127;
    float s = scores[(AA + a) * HWH + h * WW + w];
    atomicAdd(&hist[score_key(s) >> 16], 1u);
}

// 2) find largest bin B with count(key>>16 >= B) >= NSEL  (parallel suffix-scan)
__global__ __launch_bounds__(1024) void k_findbin(const unsigned* __restrict__ hist,
                                                  unsigned* __restrict__ binB) {
    __shared__ unsigned seg[1024];
    int t = threadIdx.x;
    unsigned local[64];
    unsigned ssum = 0;
#pragma unroll
    for (int k = 0; k < 64; ++k) { local[k] = hist[t * 64 + k]; ssum += local[k]; }
    seg[t] = ssum;
    __syncthreads();
    for (int off = 1; off < 1024; off <<= 1) {
        unsigned v = seg[t];
        unsigned add = (t + off < 1024) ? seg[t + off] : 0u;
        __syncthreads();
        seg[t] = v + add;
        __syncthreads();
    }
    unsigned above = (t + 1 < 1024) ? seg[t + 1] : 0u;
    if (above < NSEL && above + ssum >= NSEL) {
        unsigned acc = above;
#pragma unroll
        for (int b = 63; b >= 0; --b) {
            acc += local[b];
            if (acc >= NSEL) { *binB = (unsigned)(t * 64 + b); break; }
        }
    }
}

// 3) gather candidates (key>>16 >= B) as packed u64 (key desc, idx asc)
__global__ void k_gather(const float* __restrict__ scores, const unsigned* __restrict__ binB,
                         unsigned* __restrict__ counter, unsigned long long* __restrict__ selKeys) {
    int i = blockIdx.x * blockDim.x + threadIdx.x;
    if (i >= KK) return;
    int a = i % AA;
    int hw = i / AA;
    int h = hw >> 7, w = hw & 127;
    float s = scores[(AA + a) * HWH + h * WW + w];
    unsigned key = score_key(s);
    if ((key >> 16) >= *binB) {
        unsigned pos = atomicAdd(counter, 1u);
        if (pos < CAP)
            selKeys[pos] = ((unsigned long long)key << 32) | (unsigned)(~(unsigned)i);
    }
}

// 4) one-block bitonic sort (descending) of 8192 u64 + fused fp64 decode/clip
__global__ __launch_bounds__(1024) void k_sortdec(const unsigned* __restrict__ counter,
                                                  const unsigned long long* __restrict__ selKeys,
                                                  const float* __restrict__ bbox,
                                                  const float* __restrict__ im_info,
                                                  float4* __restrict__ boxes) {
    __shared__ unsigned long long sk[CAP];
    int t = threadIdx.x;
    unsigned cnt = *counter;
    if (cnt > CAP) cnt = CAP;
    for (int p = t; p < CAP; p += 1024) sk[p] = (p < (int)cnt) ? selKeys[p] : 0ull;
    __syncthreads();
    for (unsigned size = 2; size <= CAP; size <<= 1) {
        for (unsigned stride = size >> 1; stride > 0; stride >>= 1) {
            for (unsigned p = (unsigned)t; p < CAP / 2; p += 1024) {
                unsigned i = 2u * p - (p & (stride - 1u));
                unsigned j = i + stride;
                bool up = (i & size) != 0;
                unsigned long long a = sk[i], b = sk[j];
                bool doswap = up ? (a > b) : (a < b);
                if (doswap) { sk[i] = b; sk[j] = a; }
            }
            __syncthreads();
        }
    }
    double xmax = (double)im_info[1] - 1.0, ymax = (double)im_info[0] - 1.0;
    for (int r = t; r < NSEL; r += 1024) {
        unsigned i = ~(unsigned)(sk[r] & 0xFFFFFFFFull);
        int a = (int)(i % AA);
        int hw = (int)(i / AA);
        int h = hw >> 7, w = hw & 127;
        double sx = 16.0 * w, sy = 16.0 * h;
        double ax1 = (double)c_ax1[a] + sx, ay1 = (double)c_ay1[a] + sy;
        double ax2 = (double)c_ax2[a] + sx, ay2 = (double)c_ay2[a] + sy;
        double aw = ax2 - ax1 + 1.0, ah = ay2 - ay1 + 1.0;
        double acx = ax1 + 0.5 * aw, acy = ay1 + 0.5 * ah;
        int base = h * WW + w;
        double d0 = (double)bbox[(4 * a + 0) * HWH + base];
        double d1 = (double)bbox[(4 * a + 1) * HWH + base];
        double d2 = (double)bbox[(4 * a + 2) * HWH + base];
        double d3 = (double)bbox[(4 * a + 3) * HWH + base];
        double pcx = d0 * aw + acx, pcy = d1 * ah + acy;
        double pw = exp(d2) * aw, ph = exp(d3) * ah;
        double x1 = fmin(fmax(pcx - 0.5 * pw, 0.0), xmax);
        double y1 = fmin(fmax(pcy - 0.5 * ph, 0.0), ymax);
        double x2 = fmin(fmax(pcx + 0.5 * pw, 0.0), xmax);
        double y2 = fmin(fmax(pcy + 0.5 * ph, 0.0), ymax);
        boxes[r] = make_float4((float)x1, (float)y1, (float)x2, (float)y2);
    }
}

// 5) suppression bitmask, wave-per-tile. Off-diag: maskT[cc][gi] bit j =
//    iou(gi, cc*64+j)>0.7 && cc*64+j>gi (coalesced stores over gi).
//    Diag tiles: store TRANSPOSED 64x64 block (column view) via ballots.
__global__ __launch_bounds__(256) void k_mask(const float4* __restrict__ boxes,
                                              unsigned long long* __restrict__ maskT) {
    __shared__ float4 cb[4][64];
    int wave = threadIdx.x >> 6, lane = threadIdx.x & 63;
    for (int L = blockIdx.x * 4 + wave; L < NTRI; L += MASK_BLOCKS * 4) {
        int rc = 0, rem = L;
        while (rem >= NCH - rc) { rem -= NCH - rc; rc++; }
        int cc = rc + rem;
        cb[wave][lane] = boxes[cc * 64 + lane];
        int gi = rc * 64 + lane;
        unsigned long long bits = 0ull;
        if (gi < NSEL) {
            float4 rb = boxes[gi];
            double rx1 = rb.x, ry1 = rb.y, rx2 = rb.z, ry2 = rb.w;
            double rarea = (rx2 - rx1 + 1.0) * (ry2 - ry1 + 1.0);
            for (int j = 0; j < 64; ++j) {
                int gj = cc * 64 + j;
                float4 c = cb[wave][j];
                double iw = fmin(rx2, (double)c.z) - fmax(rx1, (double)c.x) + 1.0;
                double ih = fmin(ry2, (double)c.w) - fmax(ry1, (double)c.y) + 1.0;
                if (gj > gi && gj < NSEL && iw > 0.0 && ih > 0.0) {
                    double inter = iw * ih;
                    double carea = ((double)c.z - (double)c.x + 1.0) * ((double)c.w - (double)c.y + 1.0);
                    double uni = rarea + carea - inter;
                    if (inter > NMS_T * uni) bits |= (1ull << j);
                }
            }
        }
        if (rc != cc) {
            if (gi < NSEL) maskT[(size_t)cc * NPAD + gi] = bits;
        } else {
            unsigned long long myword = 0ull;
            for (int j = 0; j < 64; ++j) {
                unsigned long long bal = __ballot((int)((bits >> j) & 1ull));
                if (lane == j) myword = bal;
            }
            maskT[(size_t)cc * NPAD + cc * 64 + lane] = myword;  // all 64 lanes write
        }
    }
}

// 6) greedy NMS: ballot scan on transposed diag, split waves, early exit,
//    stable compaction + output.
__global__ __launch_bounds__(1024) void k_nms(const unsigned long long* __restrict__ maskT,
                                              const float4* __restrict__ boxes,
                                              float4* __restrict__ out) {
    __shared__ unsigned long long removed[NCH];
    __shared__ unsigned long long aliveSh[2];
    __shared__ int cstop;
    __shared__ unsigned scanBuf[1024];
    int t = threadIdx.x;
    int wave = t >> 6, lane = t & 63;

    if (t < NCH) removed[t] = (t == NCH - 1) ? 0xFFFF000000000000ull : 0ull;
    if (t == 0) cstop = -1;
    __syncthreads();

    unsigned long long colA = 0, wAr = 0, colB = 0, wBr = 0;  // wave0 regs
    unsigned long long mA[7], mB[7];                           // waves 1-15
    if (wave == 0) {
        colA = maskT[(size_t)0 * NPAD + 0 * 64 + lane];
        wAr = maskT[(size_t)1 * NPAD + 0 * 64 + lane];
        colB = maskT[(size_t)1 * NPAD + 1 * 64 + lane];
        wBr = maskT[(size_t)2 * NPAD + 1 * 64 + lane];
    } else {
#pragma unroll
        for (int q = 0; q < 7; ++q) {
            int w = 2 + (wave - 1) + 15 * q;
            mA[q] = (w < NCH) ? maskT[(size_t)w * NPAD + 0 * 64 + lane] : 0ull;
        }
#pragma unroll
        for (int q = 0; q < 7; ++q) {
            int w = 3 + (wave - 1) + 15 * q;
            mB[q] = (w < NCH) ? maskT[(size_t)w * NPAD + 1 * 64 + lane] : 0ull;
        }
    }
    unsigned keptTot = 0;

    for (int c = 0; c < NCH; c += 2) {
        // ---- even chunk c (wave0: scan + word c+1; then barrier) ----
        if (wave == 0) {
            unsigned long long rem = removed[c];
            unsigned alo = __builtin_amdgcn_readfirstlane((unsigned)(~rem));
            unsigned ahi = __builtin_amdgcn_readfirstlane((unsigned)((~rem) >> 32));
            unsigned long long alive = ((unsigned long long)ahi << 32) | alo;
            unsigned long long rest = alive;
            while (rest) {
                int i = __ffsll((long long)rest) - 1;
                unsigned long long sup = __ballot((int)((colA >> i) & 1ull));
                alive &= ~sup;
                rest &= ~sup;
                rest &= rest - 1ull;
            }
            keptTot += (unsigned)__popcll(alive);
            if (lane == 0) {
                removed[c] = ~alive;
                aliveSh[0] = alive;
                if (keptTot >= NOUT) cstop = c;
            }
            if (c + 1 < NCH) {
                unsigned long long sel = 0ull - ((alive >> lane) & 1ull);
                unsigned long long v = wAr & sel;
                unsigned lo = wave_or32((unsigned)v);
                unsigned hi = wave_or32((unsigned)(v >> 32));
                if (lane == 63) atomicOr(&removed[c + 1], ((unsigned long long)hi << 32) | lo);
            }
            if (c + 2 < NCH) {
                colA = maskT[(size_t)(c + 2) * NPAD + (c + 2) * 64 + lane];
                wAr = (c + 3 < NCH) ? maskT[(size_t)(c + 3) * NPAD + (c + 2) * 64 + lane] : 0ull;
            }
        }
        __syncthreads();  // B1
        if (cstop >= 0) break;
        if (wave > 0) {
            unsigned long long alive = aliveSh[0];
            unsigned long long sel = 0ull - ((alive >> lane) & 1ull);
#pragma unroll
            for (int q = 0; q < 7; ++q) {
                int w = c + 2 + (wave - 1) + 15 * q;
                if (w < NCH) {
                    unsigned long long v = mA[q] & sel;
                    unsigned lo = wave_or32((unsigned)v);
                    unsigned hi = wave_or32((unsigned)(v >> 32));
                    if (lane == 63) atomicOr(&removed[w], ((unsigned long long)hi << 32) | lo);
                }
            }
#pragma unroll
            for (int q = 0; q < 7; ++q) {
                int w = (c + 2) + 2 + (wave - 1) + 15 * q;
                mA[q] = (w < NCH) ? maskT[(size_t)w * NPAD + (c + 2) * 64 + lane] : 0ull;
            }
        }
        // ---- odd chunk c+1 (wave0, concurrent with the OR above) ----
        if (wave == 0) {
            unsigned long long rem = removed[c + 1];
            unsigned alo = __builtin_amdgcn_readfirstlane((unsigned)(~rem));
            unsigned ahi = __builtin_amdgcn_readfirstlane((unsigned)((~rem) >> 32));
            unsigned long long alive = ((unsigned long long)ahi << 32) | alo;
            unsigned long long rest = alive;
            while (rest) {
                int i = __ffsll((long long)rest) - 1;
                unsigned long long sup = __ballot((int)((colB >> i) & 1ull));
                alive &= ~sup;
                rest &= ~sup;
                rest &= rest - 1ull;
            }
            keptTot += (unsigned)__popcll(alive);
            if (lane == 0) {
                removed[c + 1] = ~alive;
                aliveSh[1] = alive;
                if (keptTot >= NOUT) cstop = c + 1;
            }
            if (c + 2 < NCH) {
                unsigned long long sel = 0ull - ((alive >> lane) & 1ull);
                unsigned long long v = wBr & sel;
                unsigned lo = wave_or32((unsigned)v);
                unsigned hi = wave_or32((unsigned)(v >> 32));
                if (lane == 63) atomicOr(&removed[c + 2], ((unsigned long long)hi << 32) | lo);
            }
            if (c + 3 < NCH) {
                colB = maskT[(size_t)(c + 3) * NPAD + (c + 3) * 64 + lane];
                wBr = (c + 4 < NCH) ? maskT[(size_t)(c + 4) * NPAD + (c + 3) * 64 + lane] : 0ull;
            }
        }
        __syncthreads();  // B2
        if (cstop >= 0) break;
        if (wave > 0) {
            unsigned long long alive = aliveSh[1];
            unsigned long long sel = 0ull - ((alive >> lane) & 1ull);
#pragma unroll
            for (int q = 0; q < 7; ++q) {
                int w = c + 3 + (wave - 1) + 15 * q;
                if (w < NCH) {
                    unsigned long long v = mB[q] & sel;
                    unsigned lo = wave_or32((unsigned)v);
                    unsigned hi = wave_or32((unsigned)(v >> 32));
                    if (lane == 63) atomicOr(&removed[w], ((unsigned long long)hi << 32) | lo);
                }
            }
#pragma unroll
            for (int q = 0; q < 7; ++q) {
                int w = (c + 3) + 2 + (wave - 1) + 15 * q;
                mB[q] = (w < NCH) ? maskT[(size_t)w * NPAD + (c + 3) * 64 + lane] : 0ull;
            }
        }
    }
    __syncthreads();

    // stable compaction: kept (index asc) then suppressed (index asc), first 1000.
    // Early-exit safety: spurious "kept" bits in unprocessed chunks land at pos >= 1000.
    int base = t * 6;
    unsigned cnt = 0, keepbits = 0;
    for (int q = 0; q < 6; ++q) {
        int i = base + q;
        if (i < NSEL) {
            bool kp = !((removed[i >> 6] >> (i & 63)) & 1ull);
            if (kp) { cnt++; keepbits |= (1u << q); }
        }
    }
    scanBuf[t] = cnt;
    __syncthreads();
    for (int off = 1; off < 1024; off <<= 1) {
        unsigned v = scanBuf[t];
        unsigned add = (t >= off) ? scanBuf[t - off] : 0u;
        __syncthreads();
        scanBuf[t] = v + add;
        __syncthreads();
    }
    unsigned incl = scanBuf[t];
    unsigned NK = scanBuf[1023];
    unsigned kpos = incl - cnt;
    for (int q = 0; q < 6; ++q) {
        int i = base + q;
        if (i < NSEL) {
            bool kp = (keepbits >> q) & 1u;
            unsigned pos = kp ? kpos : (NK + (unsigned)i - kpos);
            if (kp) kpos++;
            if (pos < NOUT) out[pos] = boxes[i];
        }
    }
}

extern "C" void kernel_launch(void* const* d_in, const int* in_sizes, int n_in,
                              void* d_out, int out_size, void* d_ws, size_t ws_size,
                              hipStream_t stream) {
    const float* scores = (const float*)d_in[0];
    const float* bbox = (const float*)d_in[1];
    const float* im_info = (const float*)d_in[2];
    char* ws = (char*)d_ws;

    unsigned* hist = (unsigned*)(ws + WS_HIST);
    unsigned* counter = (unsigned*)(ws + WS_COUNTER);
    unsigned* binB = (unsigned*)(ws + WS_BINB);
    unsigned long long* selKeys = (unsigned long long*)(ws + WS_SELKEYS);
    float4* boxes = (float4*)(ws + WS_BOXES);
    unsigned long long* maskT = (unsigned long long*)(ws + WS_MASK);
    float4* out = (float4*)d_out;

    hipMemsetAsync(ws, 0, WS_ZERO_BYTES, stream);

    k_hist<<<(KK + 255) / 256, 256, 0, stream>>>(scores, hist);
    k_findbin<<<1, 1024, 0, stream>>>(hist, binB);
    k_gather<<<(KK + 255) / 256, 256, 0, stream>>>(scores, binB, counter, selKeys);
    k_sortdec<<<1, 1024, 0, stream>>>(counter, selKeys, bbox, im_info, boxes);
    k_mask<<<MASK_BLOCKS, 256, 0, stream>>>(boxes, maskT);
    k_nms<<<1, 1024, 0, stream>>>(maskT, boxes, out);
}

// Round 6
// 188.475 us; speedup vs baseline: 3.0678x; 1.3336x over previous
//
#include <hip/hip_runtime.h>
#include <cstdint>

#define HH 76
#define WW 128
#define AA 9
#define HWH (HH * WW)          // 9728
#define KK (HWH * AA)          // 87552
#define NSEL 6000
#define NCH 94                 // ceil(6000/64)
#define NPAD (NCH * 64)        // 6016
#define NOUT 1000
#define NMS_T 0.7
#define NTRI (NCH * (NCH + 1) / 2)  // 4465 upper-tri tiles
#define MASK_BLOCKS 1117            // ceil(NTRI/4) wave-per-tile
#define SELCAP 16384
#define BINCAP 2048                 // max elements sorted per bin (real ~400)

// ---- workspace layout (bytes) ----
#define WS_HIST 0              // u32[65536]                      (zeroed)
#define WS_BINB 262144         // u32 threshold bin               (zeroed)
#define WS_NACT 262148         // u32 active-bin count            (zeroed)
#define WS_ZERO_BYTES 262208   // zero prefix per replay
#define WS_ACTIVE 262208       // u32[8192] active bin list
#define WS_BINBASE 294976      // u32[65536] rank base per bin (written by findbin for bins>=B)
#define WS_SELKEYS 557120      // u64[16384]
#define WS_BOXES 688192        // float4[6016] (16-aligned)
#define WS_MASK 784448         // u64 maskT[NCH][NPAD]; diag words hold TRANSPOSED diag

// base anchors from generate_anchors() (numpy fp64, exact small values)
__device__ __constant__ float c_ax1[9] = {-84.f, -176.f, -360.f, -56.f, -120.f, -248.f, -36.f, -80.f, -168.f};
__device__ __constant__ float c_ay1[9] = {-40.f, -88.f, -184.f, -56.f, -120.f, -248.f, -80.f, -168.f, -344.f};
__device__ __constant__ float c_ax2[9] = {99.f, 191.f, 375.f, 71.f, 135.f, 263.f, 51.f, 95.f, 183.f};
__device__ __constant__ float c_ay2[9] = {55.f, 103.f, 199.f, 71.f, 135.f, 263.f, 95.f, 183.f, 359.f};

__device__ __forceinline__ unsigned score_key(float s) {
    unsigned u = __float_as_uint(s);
    return (u & 0x80000000u) ? ~u : (u | 0x80000000u);
}

// 64-lane OR-reduce via DPP (result valid in lane 63). OR idempotent -> bcast quirks harmless.
__device__ __forceinline__ unsigned wave_or32(unsigned v) {
    v |= (unsigned)__builtin_amdgcn_update_dpp(0, (int)v, 0x111, 0xf, 0xf, true);
    v |= (unsigned)__builtin_amdgcn_update_dpp(0, (int)v, 0x112, 0xf, 0xf, true);
    v |= (unsigned)__builtin_amdgcn_update_dpp(0, (int)v, 0x114, 0xf, 0xf, true);
    v |= (unsigned)__builtin_amdgcn_update_dpp(0, (int)v, 0x118, 0xf, 0xf, true);
    v |= (unsigned)__builtin_amdgcn_update_dpp(0, (int)v, 0x142, 0xf, 0xf, true);
    v |= (unsigned)__builtin_amdgcn_update_dpp(0, (int)v, 0x143, 0xf, 0xf, true);
    return v;
}

// 1) histogram over top-16 bits of orderable score key
__global__ void k_hist(const float* __restrict__ scores, unsigned* __restrict__ hist) {
    int i = blockIdx.x * blockDim.x + threadIdx.x;
    if (i >= KK) return;
    int a = i % AA;
    int hw = i / AA;
    int h = hw >> 7, w = hw & 127;
    float s = scores[(AA + a) * HWH + h * WW + w];
    atomicAdd(&hist[score_key(s) >> 16], 1u);
}

// 2) find threshold bin B (suffix>=NSEL); emit rank base + active list for bins >= B
__global__ __launch_bounds__(1024) void k_findbin(const unsigned* __restrict__ hist,
                                                  unsigned* __restrict__ binB,
                                                  unsigned* __restrict__ binBase,
                                                  unsigned* __restrict__ activeList,
                                                  unsigned* __restrict__ nact) {
    __shared__ unsigned seg[1024];
    __shared__ unsigned Bsh;
    int t = threadIdx.x;
    unsigned local[64];
    unsigned ssum = 0;
#pragma unroll
    for (int k = 0; k < 64; ++k) { local[k] = hist[t * 64 + k]; ssum += local[k]; }
    seg[t] = ssum;
    __syncthreads();
    for (int off = 1; off < 1024; off <<= 1) {
        unsigned v = seg[t];
        unsigned add = (t + off < 1024) ? seg[t + off] : 0u;
        __syncthreads();
        seg[t] = v + add;
        __syncthreads();
    }
    unsigned above = (t + 1 < 1024) ? seg[t + 1] : 0u;
    if (above < NSEL && above + ssum >= NSEL) {
        unsigned acc = above;
#pragma unroll
        for (int b = 63; b >= 0; --b) {
            acc += local[b];
            if (acc >= NSEL) { Bsh = (unsigned)(t * 64 + b); *binB = Bsh; break; }
        }
    }
    __syncthreads();
    unsigned B = Bsh;
    if ((unsigned)(t * 64 + 63) >= B) {
        unsigned acc2 = above;
        for (int k = 63; k >= 0; --k) {
            unsigned bin = (unsigned)(t * 64 + k);
            if (bin < B) break;
            if (local[k] > 0) {
                binBase[bin] = acc2;                    // global rank base (count above)
                unsigned tick = atomicAdd(nact, 1u);
                if (tick < 8192) activeList[tick] = bin;
            }
            acc2 += local[k];
        }
    }
}

// 3) gather candidates directly into rank-segmented slots (binBase advances per hit)
__global__ void k_gather(const float* __restrict__ scores, const unsigned* __restrict__ binB,
                         unsigned* __restrict__ binBase, unsigned long long* __restrict__ selKeys) {
    int i = blockIdx.x * blockDim.x + threadIdx.x;
    if (i >= KK) return;
    int a = i % AA;
    int hw = i / AA;
    int h = hw >> 7, w = hw & 127;
    float s = scores[(AA + a) * HWH + h * WW + w];
    unsigned key = score_key(s);
    unsigned bin = key >> 16;
    if (bin >= *binB) {
        unsigned pos = atomicAdd(&binBase[bin], 1u);
        if (pos < SELCAP)
            selKeys[pos] = ((unsigned long long)key << 32) | (unsigned)(~(unsigned)i);
    }
}

// 4) per-bin bitonic sort (descending) + fused fp64 decode/clip into boxes[rank]
__global__ __launch_bounds__(256) void k_binsort(const unsigned* __restrict__ hist,
                                                 const unsigned* __restrict__ binBase,
                                                 const unsigned* __restrict__ activeList,
                                                 const unsigned* __restrict__ nact,
                                                 unsigned long long* __restrict__ selKeys,
                                                 const float* __restrict__ bbox,
                                                 const float* __restrict__ im_info,
                                                 float4* __restrict__ boxes) {
    __shared__ unsigned long long sk[BINCAP];
    int t = threadIdx.x;
    unsigned na = *nact;
    if (na > 8192) na = 8192;
    double xmax = (double)im_info[1] - 1.0, ymax = (double)im_info[0] - 1.0;
    for (unsigned aIdx = blockIdx.x; aIdx < na; aIdx += gridDim.x) {
        unsigned bin = activeList[aIdx];
        unsigned ntot = hist[bin];
        unsigned base = binBase[bin] - ntot;  // post-gather: binBase = origBase + ntot
        unsigned n = ntot > BINCAP ? BINCAP : ntot;
        unsigned m = 64; while (m < n) m <<= 1;
        for (unsigned p = t; p < m; p += 256) sk[p] = (p < n) ? selKeys[base + p] : 0ull;
        __syncthreads();
        for (unsigned size = 2; size <= m; size <<= 1) {
            for (unsigned stride = size >> 1; stride > 0; stride >>= 1) {
                for (unsigned p = (unsigned)t; p < m / 2; p += 256) {
                    unsigned i = 2u * p - (p & (stride - 1u));
                    unsigned j = i + stride;
                    bool up = (i & size) != 0;
                    unsigned long long a = sk[i], b = sk[j];
                    bool doswap = up ? (a > b) : (a < b);
                    if (doswap) { sk[i] = b; sk[j] = a; }
                }
                __syncthreads();
            }
        }
        for (unsigned r = t; r < n; r += 256) {
            unsigned g = base + r;
            if (g >= NSEL) continue;
            unsigned i = ~(unsigned)(sk[r] & 0xFFFFFFFFull);
            int a = (int)(i % AA);
            int hw = (int)(i / AA);
            int h = hw >> 7, w = hw & 127;
            double sx = 16.0 * w, sy = 16.0 * h;
            double ax1 = (double)c_ax1[a] + sx, ay1 = (double)c_ay1[a] + sy;
            double ax2 = (double)c_ax2[a] + sx, ay2 = (double)c_ay2[a] + sy;
            double aw = ax2 - ax1 + 1.0, ah = ay2 - ay1 + 1.0;
            double acx = ax1 + 0.5 * aw, acy = ay1 + 0.5 * ah;
            int bse = h * WW + w;
            double d0 = (double)bbox[(4 * a + 0) * HWH + bse];
            double d1 = (double)bbox[(4 * a + 1) * HWH + bse];
            double d2 = (double)bbox[(4 * a + 2) * HWH + bse];
            double d3 = (double)bbox[(4 * a + 3) * HWH + bse];
            double pcx = d0 * aw + acx, pcy = d1 * ah + acy;
            double pw = exp(d2) * aw, ph = exp(d3) * ah;
            double x1 = fmin(fmax(pcx - 0.5 * pw, 0.0), xmax);
            double y1 = fmin(fmax(pcy - 0.5 * ph, 0.0), ymax);
            double x2 = fmin(fmax(pcx + 0.5 * pw, 0.0), xmax);
            double y2 = fmin(fmax(pcy + 0.5 * ph, 0.0), ymax);
            boxes[g] = make_float4((float)x1, (float)y1, (float)x2, (float)y2);
        }
        __syncthreads();
    }
}

// 5) suppression bitmask, wave-per-tile. Off-diag: maskT[cc][gi] bit j =
//    iou(gi, cc*64+j)>0.7 && cc*64+j>gi. Diag tiles: TRANSPOSED block via ballots.
__global__ __launch_bounds__(256) void k_mask(const float4* __restrict__ boxes,
                                              unsigned long long* __restrict__ maskT) {
    __shared__ float4 cb[4][64];
    int wave = threadIdx.x >> 6, lane = threadIdx.x & 63;
    for (int L = blockIdx.x * 4 + wave; L < NTRI; L += MASK_BLOCKS * 4) {
        int rc = 0, rem = L;
        while (rem >= NCH - rc) { rem -= NCH - rc; rc++; }
        int cc = rc + rem;
        cb[wave][lane] = boxes[cc * 64 + lane];
        int gi = rc * 64 + lane;
        unsigned long long bits = 0ull;
        if (gi < NSEL) {
            float4 rb = boxes[gi];
            double rx1 = rb.x, ry1 = rb.y, rx2 = rb.z, ry2 = rb.w;
            double rarea = (rx2 - rx1 + 1.0) * (ry2 - ry1 + 1.0);
            for (int j = 0; j < 64; ++j) {
                int gj = cc * 64 + j;
                float4 c = cb[wave][j];
                double iw = fmin(rx2, (double)c.z) - fmax(rx1, (double)c.x) + 1.0;
                double ih = fmin(ry2, (double)c.w) - fmax(ry1, (double)c.y) + 1.0;
                if (gj > gi && gj < NSEL && iw > 0.0 && ih > 0.0) {
                    double inter = iw * ih;
                    double carea = ((double)c.z - (double)c.x + 1.0) * ((double)c.w - (double)c.y + 1.0);
                    double uni = rarea + carea - inter;
                    if (inter > NMS_T * uni) bits |= (1ull << j);
                }
            }
        }
        if (rc != cc) {
            if (gi < NSEL) maskT[(size_t)cc * NPAD + gi] = bits;
        } else {
            unsigned long long myword = 0ull;
            for (int j = 0; j < 64; ++j) {
                unsigned long long bal = __ballot((int)((bits >> j) & 1ull));
                if (lane == j) myword = bal;
            }
            maskT[(size_t)cc * NPAD + cc * 64 + lane] = myword;
        }
    }
}

// 6) greedy NMS: ballot scan on transposed diag, split waves, early exit,
//    stable compaction + output.
__global__ __launch_bounds__(1024) void k_nms(const unsigned long long* __restrict__ maskT,
                                              const float4* __restrict__ boxes,
                                              float4* __restrict__ out) {
    __shared__ unsigned long long removed[NCH];
    __shared__ unsigned long long aliveSh[2];
    __shared__ int cstop;
    __shared__ unsigned scanBuf[1024];
    int t = threadIdx.x;
    int wave = t >> 6, lane = t & 63;

    if (t < NCH) removed[t] = (t == NCH - 1) ? 0xFFFF000000000000ull : 0ull;
    if (t == 0) cstop = -1;
    __syncthreads();

    unsigned long long colA = 0, wAr = 0, colB = 0, wBr = 0;  // wave0 regs
    unsigned long long mA[7], mB[7];                           // waves 1-15
    if (wave == 0) {
        colA = maskT[(size_t)0 * NPAD + 0 * 64 + lane];
        wAr = maskT[(size_t)1 * NPAD + 0 * 64 + lane];
        colB = maskT[(size_t)1 * NPAD + 1 * 64 + lane];
        wBr = maskT[(size_t)2 * NPAD + 1 * 64 + lane];
    } else {
#pragma unroll
        for (int q = 0; q < 7; ++q) {
            int w = 2 + (wave - 1) + 15 * q;
            mA[q] = (w < NCH) ? maskT[(size_t)w * NPAD + 0 * 64 + lane] : 0ull;
        }
#pragma unroll
        for (int q = 0; q < 7; ++q) {
            int w = 3 + (wave - 1) + 15 * q;
            mB[q] = (w < NCH) ? maskT[(size_t)w * NPAD + 1 * 64 + lane] : 0ull;
        }
    }
    unsigned keptTot = 0;

    for (int c = 0; c < NCH; c += 2) {
        if (wave == 0) {
            unsigned long long rem = removed[c];
            unsigned alo = __builtin_amdgcn_readfirstlane((unsigned)(~rem));
            unsigned ahi = __builtin_amdgcn_readfirstlane((unsigned)((~rem) >> 32));
            unsigned long long alive = ((unsigned long long)ahi << 32) | alo;
            unsigned long long rest = alive;
            while (rest) {
                int i = __ffsll((long long)rest) - 1;
                unsigned long long sup = __ballot((int)((colA >> i) & 1ull));
                alive &= ~sup;
                rest &= ~sup;
                rest &= rest - 1ull;
            }
            keptTot += (unsigned)__popcll(alive);
            if (lane == 0) {
                removed[c] = ~alive;
                aliveSh[0] = alive;
                if (keptTot >= NOUT) cstop = c;
            }
            if (c + 1 < NCH) {
                unsigned long long sel = 0ull - ((alive >> lane) & 1ull);
                unsigned long long v = wAr & sel;
                unsigned lo = wave_or32((unsigned)v);
                unsigned hi = wave_or32((unsigned)(v >> 32));
                if (lane == 63) atomicOr(&removed[c + 1], ((unsigned long long)hi << 32) | lo);
            }
            if (c + 2 < NCH) {
                colA = maskT[(size_t)(c + 2) * NPAD + (c + 2) * 64 + lane];
                wAr = (c + 3 < NCH) ? maskT[(size_t)(c + 3) * NPAD + (c + 2) * 64 + lane] : 0ull;
            }
        }
        __syncthreads();  // B1
        if (cstop >= 0) break;
        if (wave > 0) {
            unsigned long long alive = aliveSh[0];
            unsigned long long sel = 0ull - ((alive >> lane) & 1ull);
#pragma unroll
            for (int q = 0; q < 7; ++q) {
                int w = c + 2 + (wave - 1) + 15 * q;
                if (w < NCH) {
                    unsigned long long v = mA[q] & sel;
                    unsigned lo = wave_or32((unsigned)v);
                    unsigned hi = wave_or32((unsigned)(v >> 32));
                    if (lane == 63) atomicOr(&removed[w], ((unsigned long long)hi << 32) | lo);
                }
            }
#pragma unroll
            for (int q = 0; q < 7; ++q) {
                int w = (c + 2) + 2 + (wave - 1) + 15 * q;
                mA[q] = (w < NCH) ? maskT[(size_t)w * NPAD + (c + 2) * 64 + lane] : 0ull;
            }
        }
        if (wave == 0) {
            unsigned long long rem = removed[c + 1];
            unsigned alo = __builtin_amdgcn_readfirstlane((unsigned)(~rem));
            unsigned ahi = __builtin_amdgcn_readfirstlane((unsigned)((~rem) >> 32));
            unsigned long long alive = ((unsigned long long)ahi << 32) | alo;
            unsigned long long rest = alive;
            while (rest) {
                int i = __ffsll((long long)rest) - 1;
                unsigned long long sup = __ballot((int)((colB >> i) & 1ull));
                alive &= ~sup;
                rest &= ~sup;
                rest &= rest - 1ull;
            }
            keptTot += (unsigned)__popcll(alive);
            if (lane == 0) {
                removed[c + 1] = ~alive;
                aliveSh[1] = alive;
                if (keptTot >= NOUT) cstop = c + 1;
            }
            if (c + 2 < NCH) {
                unsigned long long sel = 0ull - ((alive >> lane) & 1ull);
                unsigned long long v = wBr & sel;
                unsigned lo = wave_or32((unsigned)v);
                unsigned hi = wave_or32((unsigned)(v >> 32));
                if (lane == 63) atomicOr(&removed[c + 2], ((unsigned long long)hi << 32) | lo);
            }
            if (c + 3 < NCH) {
                colB = maskT[(size_t)(c + 3) * NPAD + (c + 3) * 64 + lane];
                wBr = (c + 4 < NCH) ? maskT[(size_t)(c + 4) * NPAD + (c + 3) * 64 + lane] : 0ull;
            }
        }
        __syncthreads();  // B2
        if (cstop >= 0) break;
        if (wave > 0) {
            unsigned long long alive = aliveSh[1];
            unsigned long long sel = 0ull - ((alive >> lane) & 1ull);
#pragma unroll
            for (int q = 0; q < 7; ++q) {
                int w = c + 3 + (wave - 1) + 15 * q;
                if (w < NCH) {
                    unsigned long long v = mB[q] & sel;
                    unsigned lo = wave_or32((unsigned)v);
                    unsigned hi = wave_or32((unsigned)(v >> 32));
                    if (lane == 63) atomicOr(&removed[w], ((unsigned long long)hi << 32) | lo);
                }
            }
#pragma unroll
            for (int q = 0; q < 7; ++q) {
                int w = (c + 3) + 2 + (wave - 1) + 15 * q;
                mB[q] = (w < NCH) ? maskT[(size_t)w * NPAD + (c + 3) * 64 + lane] : 0ull;
            }
        }
    }
    __syncthreads();

    // stable compaction: kept (index asc) then suppressed (index asc), first 1000.
    int base = t * 6;
    unsigned cnt = 0, keepbits = 0;
    for (int q = 0; q < 6; ++q) {
        int i = base + q;
        if (i < NSEL) {
            bool kp = !((removed[i >> 6] >> (i & 63)) & 1ull);
            if (kp) { cnt++; keepbits |= (1u << q); }
        }
    }
    scanBuf[t] = cnt;
    __syncthreads();
    for (int off = 1; off < 1024; off <<= 1) {
        unsigned v = scanBuf[t];
        unsigned add = (t >= off) ? scanBuf[t - off] : 0u;
        __syncthreads();
        scanBuf[t] = v + add;
        __syncthreads();
    }
    unsigned incl = scanBuf[t];
    unsigned NK = scanBuf[1023];
    unsigned kpos = incl - cnt;
    for (int q = 0; q < 6; ++q) {
        int i = base + q;
        if (i < NSEL) {
            bool kp = (keepbits >> q) & 1u;
            unsigned pos = kp ? kpos : (NK + (unsigned)i - kpos);
            if (kp) kpos++;
            if (pos < NOUT) out[pos] = boxes[i];
        }
    }
}

extern "C" void kernel_launch(void* const* d_in, const int* in_sizes, int n_in,
                              void* d_out, int out_size, void* d_ws, size_t ws_size,
                              hipStream_t stream) {
    const float* scores = (const float*)d_in[0];
    const float* bbox = (const float*)d_in[1];
    const float* im_info = (const float*)d_in[2];
    char* ws = (char*)d_ws;

    unsigned* hist = (unsigned*)(ws + WS_HIST);
    unsigned* binB = (unsigned*)(ws + WS_BINB);
    unsigned* nact = (unsigned*)(ws + WS_NACT);
    unsigned* activeList = (unsigned*)(ws + WS_ACTIVE);
    unsigned* binBase = (unsigned*)(ws + WS_BINBASE);
    unsigned long long* selKeys = (unsigned long long*)(ws + WS_SELKEYS);
    float4* boxes = (float4*)(ws + WS_BOXES);
    unsigned long long* maskT = (unsigned long long*)(ws + WS_MASK);
    float4* out = (float4*)d_out;

    hipMemsetAsync(ws, 0, WS_ZERO_BYTES, stream);

    k_hist<<<(KK + 255) / 256, 256, 0, stream>>>(scores, hist);
    k_findbin<<<1, 1024, 0, stream>>>(hist, binB, binBase, activeList, nact);
    k_gather<<<(KK + 255) / 256, 256, 0, stream>>>(scores, binB, binBase, selKeys);
    k_binsort<<<64, 256, 0, stream>>>(hist, binBase, activeList, nact, selKeys, bbox, im_info, boxes);
    k_mask<<<MASK_BLOCKS, 256, 0, stream>>>(boxes, maskT);
    k_nms<<<1, 1024, 0, stream>>>(maskT, boxes, out);
}

// Round 7
// 187.833 us; speedup vs baseline: 3.0783x; 1.0034x over previous
//
#include <hip/hip_runtime.h>
#include <cstdint>

#define HH 76
#define WW 128
#define AA 9
#define HWH (HH * WW)          // 9728
#define KK (HWH * AA)          // 87552
#define NSEL 6000
#define NCH 94                 // ceil(6000/64)
#define NPAD (NCH * 64)        // 6016
#define NOUT 1000
#define NMS_T 0.7
#define NTRI (NCH * (NCH + 1) / 2)  // 4465 upper-tri tiles
#define MASK_BLOCKS 1117            // ceil(NTRI/4) wave-per-tile
#define SELCAP 16384
#define BINCAP 2048                 // max elements sorted per bin (real ~700)

// ---- workspace layout (bytes) ----
#define WS_HIST 0              // u32[65536]                      (zeroed)
#define WS_BINB 262144         // u32 threshold bin               (zeroed)
#define WS_NACT 262148         // u32 active-bin count            (zeroed)
#define WS_ZERO_BYTES 262208   // zero prefix per replay
#define WS_ACTIVE 262208       // u32[8192] active bin list
#define WS_BINBASE 294976      // u32[65536] rank base per bin
#define WS_SELKEYS 557120      // u64[16384]
#define WS_BOXES 688192        // float4[6016] (16-aligned)
#define WS_MASK 784448         // u64 maskT[NCH][NPAD]; diag words hold TRANSPOSED diag

// base anchors from generate_anchors() (numpy fp64, exact small values)
__device__ __constant__ float c_ax1[9] = {-84.f, -176.f, -360.f, -56.f, -120.f, -248.f, -36.f, -80.f, -168.f};
__device__ __constant__ float c_ay1[9] = {-40.f, -88.f, -184.f, -56.f, -120.f, -248.f, -80.f, -168.f, -344.f};
__device__ __constant__ float c_ax2[9] = {99.f, 191.f, 375.f, 71.f, 135.f, 263.f, 51.f, 95.f, 183.f};
__device__ __constant__ float c_ay2[9] = {55.f, 103.f, 199.f, 71.f, 135.f, 263.f, 95.f, 183.f, 359.f};

__device__ __forceinline__ unsigned score_key(float s) {
    unsigned u = __float_as_uint(s);
    return (u & 0x80000000u) ? ~u : (u | 0x80000000u);
}

// 64-lane OR-reduce via DPP (result valid in lane 63). OR idempotent -> bcast quirks harmless.
__device__ __forceinline__ unsigned wave_or32(unsigned v) {
    v |= (unsigned)__builtin_amdgcn_update_dpp(0, (int)v, 0x111, 0xf, 0xf, true);
    v |= (unsigned)__builtin_amdgcn_update_dpp(0, (int)v, 0x112, 0xf, 0xf, true);
    v |= (unsigned)__builtin_amdgcn_update_dpp(0, (int)v, 0x114, 0xf, 0xf, true);
    v |= (unsigned)__builtin_amdgcn_update_dpp(0, (int)v, 0x118, 0xf, 0xf, true);
    v |= (unsigned)__builtin_amdgcn_update_dpp(0, (int)v, 0x142, 0xf, 0xf, true);
    v |= (unsigned)__builtin_amdgcn_update_dpp(0, (int)v, 0x143, 0xf, 0xf, true);
    return v;
}

// greedy in-chunk scan with 4-wide speculative ballots.
// col = transposed diag word (lane j holds bit i = "box i suppresses box j", i<j).
// alive (uniform) is updated; returns final alive.
__device__ __forceinline__ unsigned long long chunk_scan(unsigned long long col,
                                                         unsigned long long alive) {
    unsigned long long rest = alive;
    while (rest) {
        unsigned long long r = rest;
        unsigned i0 = (unsigned)__builtin_ctzll(r); r &= r - 1;
        unsigned i1 = 64, i2 = 64, i3 = 64;
        if (r) { i1 = (unsigned)__builtin_ctzll(r); r &= r - 1;
            if (r) { i2 = (unsigned)__builtin_ctzll(r); r &= r - 1;
                if (r) { i3 = (unsigned)__builtin_ctzll(r); r &= r - 1; } } }
        // 4 independent ballots (VALU pipelined)
        unsigned long long s0 = __ballot((int)((col >> i0) & 1ull));
        unsigned long long s1 = __ballot((int)((col >> (i1 & 63)) & 1ull));
        unsigned long long s2 = __ballot((int)((col >> (i2 & 63)) & 1ull));
        unsigned long long s3 = __ballot((int)((col >> (i3 & 63)) & 1ull));
        // serial SALU merge (exact greedy semantics)
        unsigned long long dead = s0;
        if (i1 < 64 && !((dead >> i1) & 1ull)) dead |= s1;
        if (i2 < 64 && !((dead >> i2) & 1ull)) dead |= s2;
        if (i3 < 64 && !((dead >> i3) & 1ull)) dead |= s3;
        alive &= ~dead;
        rest = r & ~dead;
    }
    return alive;
}

// 1) histogram over top-16 bits of orderable score key (linear float4 reads)
__global__ void k_hist(const float* __restrict__ scores, unsigned* __restrict__ hist) {
    int j4 = blockIdx.x * blockDim.x + threadIdx.x;
    if (j4 >= KK / 4) return;
    float4 v = ((const float4*)(scores + AA * HWH))[j4];
    atomicAdd(&hist[score_key(v.x) >> 16], 1u);
    atomicAdd(&hist[score_key(v.y) >> 16], 1u);
    atomicAdd(&hist[score_key(v.z) >> 16], 1u);
    atomicAdd(&hist[score_key(v.w) >> 16], 1u);
}

// 2) find threshold bin B (suffix>=NSEL); emit rank base + active list for bins >= B
__global__ __launch_bounds__(1024) void k_findbin(const unsigned* __restrict__ hist,
                                                  unsigned* __restrict__ binB,
                                                  unsigned* __restrict__ binBase,
                                                  unsigned* __restrict__ activeList,
                                                  unsigned* __restrict__ nact) {
    __shared__ unsigned seg[1024];
    __shared__ unsigned Bsh;
    int t = threadIdx.x;
    unsigned local[64];
    unsigned ssum = 0;
#pragma unroll
    for (int k = 0; k < 64; ++k) { local[k] = hist[t * 64 + k]; ssum += local[k]; }
    seg[t] = ssum;
    __syncthreads();
    for (int off = 1; off < 1024; off <<= 1) {
        unsigned v = seg[t];
        unsigned add = (t + off < 1024) ? seg[t + off] : 0u;
        __syncthreads();
        seg[t] = v + add;
        __syncthreads();
    }
    unsigned above = (t + 1 < 1024) ? seg[t + 1] : 0u;
    if (above < NSEL && above + ssum >= NSEL) {
        unsigned acc = above;
#pragma unroll
        for (int b = 63; b >= 0; --b) {
            acc += local[b];
            if (acc >= NSEL) { Bsh = (unsigned)(t * 64 + b); *binB = Bsh; break; }
        }
    }
    __syncthreads();
    unsigned B = Bsh;
    if ((unsigned)(t * 64 + 63) >= B) {
        unsigned acc2 = above;
        for (int k = 63; k >= 0; --k) {
            unsigned bin = (unsigned)(t * 64 + k);
            if (bin < B) break;
            if (local[k] > 0) {
                binBase[bin] = acc2;
                unsigned tick = atomicAdd(nact, 1u);
                if (tick < 8192) activeList[tick] = bin;
            }
            acc2 += local[k];
        }
    }
}

// 3) gather into rank-segmented slots (linear float4 reads; anchor index derived)
__global__ void k_gather(const float* __restrict__ scores, const unsigned* __restrict__ binB,
                         unsigned* __restrict__ binBase, unsigned long long* __restrict__ selKeys) {
    int j4 = blockIdx.x * blockDim.x + threadIdx.x;
    if (j4 >= KK / 4) return;
    float4 v = ((const float4*)(scores + AA * HWH))[j4];
    unsigned B = *binB;
    float sv[4] = {v.x, v.y, v.z, v.w};
#pragma unroll
    for (int k = 0; k < 4; ++k) {
        int j = j4 * 4 + k;            // linear index in fg storage (a*HWH + hw)
        unsigned key = score_key(sv[k]);
        unsigned bin = key >> 16;
        if (bin >= B) {
            int a = j / HWH;
            int hw = j - a * HWH;
            unsigned i = (unsigned)(hw * AA + a);  // anchor-order index (tie-break)
            unsigned pos = atomicAdd(&binBase[bin], 1u);
            if (pos < SELCAP)
                selKeys[pos] = ((unsigned long long)key << 32) | (unsigned)(~i);
        }
    }
}

// 4) per-bin bitonic sort (descending) + fused fp64 decode/clip into boxes[rank]
__global__ __launch_bounds__(256) void k_binsort(const unsigned* __restrict__ hist,
                                                 const unsigned* __restrict__ binBase,
                                                 const unsigned* __restrict__ activeList,
                                                 const unsigned* __restrict__ nact,
                                                 unsigned long long* __restrict__ selKeys,
                                                 const float* __restrict__ bbox,
                                                 const float* __restrict__ im_info,
                                                 float4* __restrict__ boxes) {
    __shared__ unsigned long long sk[BINCAP];
    int t = threadIdx.x;
    unsigned na = *nact;
    if (na > 8192) na = 8192;
    double xmax = (double)im_info[1] - 1.0, ymax = (double)im_info[0] - 1.0;
    for (unsigned aIdx = blockIdx.x; aIdx < na; aIdx += gridDim.x) {
        unsigned bin = activeList[aIdx];
        unsigned ntot = hist[bin];
        unsigned base = binBase[bin] - ntot;  // post-gather: binBase = origBase + ntot
        unsigned n = ntot > BINCAP ? BINCAP : ntot;
        unsigned m = 64; while (m < n) m <<= 1;
        for (unsigned p = t; p < m; p += 256) sk[p] = (p < n) ? selKeys[base + p] : 0ull;
        __syncthreads();
        for (unsigned size = 2; size <= m; size <<= 1) {
            for (unsigned stride = size >> 1; stride > 0; stride >>= 1) {
                for (unsigned p = (unsigned)t; p < m / 2; p += 256) {
                    unsigned i = 2u * p - (p & (stride - 1u));
                    unsigned j = i + stride;
                    bool up = (i & size) != 0;
                    unsigned long long a = sk[i], b = sk[j];
                    bool doswap = up ? (a > b) : (a < b);
                    if (doswap) { sk[i] = b; sk[j] = a; }
                }
                __syncthreads();
            }
        }
        for (unsigned r = t; r < n; r += 256) {
            unsigned g = base + r;
            if (g >= NSEL) continue;
            unsigned i = ~(unsigned)(sk[r] & 0xFFFFFFFFull);
            int a = (int)(i % AA);
            int hw = (int)(i / AA);
            int h = hw >> 7, w = hw & 127;
            double sx = 16.0 * w, sy = 16.0 * h;
            double ax1 = (double)c_ax1[a] + sx, ay1 = (double)c_ay1[a] + sy;
            double ax2 = (double)c_ax2[a] + sx, ay2 = (double)c_ay2[a] + sy;
            double aw = ax2 - ax1 + 1.0, ah = ay2 - ay1 + 1.0;
            double acx = ax1 + 0.5 * aw, acy = ay1 + 0.5 * ah;
            int bse = h * WW + w;
            double d0 = (double)bbox[(4 * a + 0) * HWH + bse];
            double d1 = (double)bbox[(4 * a + 1) * HWH + bse];
            double d2 = (double)bbox[(4 * a + 2) * HWH + bse];
            double d3 = (double)bbox[(4 * a + 3) * HWH + bse];
            double pcx = d0 * aw + acx, pcy = d1 * ah + acy;
            double pw = exp(d2) * aw, ph = exp(d3) * ah;
            double x1 = fmin(fmax(pcx - 0.5 * pw, 0.0), xmax);
            double y1 = fmin(fmax(pcy - 0.5 * ph, 0.0), ymax);
            double x2 = fmin(fmax(pcx + 0.5 * pw, 0.0), xmax);
            double y2 = fmin(fmax(pcy + 0.5 * ph, 0.0), ymax);
            boxes[g] = make_float4((float)x1, (float)y1, (float)x2, (float)y2);
        }
        __syncthreads();
    }
}

// 5) suppression bitmask, wave-per-tile. Off-diag: maskT[cc][gi] bit j =
//    iou(gi, cc*64+j)>0.7 && cc*64+j>gi. Diag tiles: TRANSPOSED block via ballots.
__global__ __launch_bounds__(256) void k_mask(const float4* __restrict__ boxes,
                                              unsigned long long* __restrict__ maskT) {
    __shared__ float4 cb[4][64];
    int wave = threadIdx.x >> 6, lane = threadIdx.x & 63;
    for (int L = blockIdx.x * 4 + wave; L < NTRI; L += MASK_BLOCKS * 4) {
        int rc = 0, rem = L;
        while (rem >= NCH - rc) { rem -= NCH - rc; rc++; }
        int cc = rc + rem;
        cb[wave][lane] = boxes[cc * 64 + lane];
        int gi = rc * 64 + lane;
        unsigned long long bits = 0ull;
        if (gi < NSEL) {
            float4 rb = boxes[gi];
            double rx1 = rb.x, ry1 = rb.y, rx2 = rb.z, ry2 = rb.w;
            double rarea = (rx2 - rx1 + 1.0) * (ry2 - ry1 + 1.0);
            for (int j = 0; j < 64; ++j) {
                int gj = cc * 64 + j;
                float4 c = cb[wave][j];
                double iw = fmin(rx2, (double)c.z) - fmax(rx1, (double)c.x) + 1.0;
                double ih = fmin(ry2, (double)c.w) - fmax(ry1, (double)c.y) + 1.0;
                if (gj > gi && gj < NSEL && iw > 0.0 && ih > 0.0) {
                    double inter = iw * ih;
                    double carea = ((double)c.z - (double)c.x + 1.0) * ((double)c.w - (double)c.y + 1.0);
                    double uni = rarea + carea - inter;
                    if (inter > NMS_T * uni) bits |= (1ull << j);
                }
            }
        }
        if (rc != cc) {
            if (gi < NSEL) maskT[(size_t)cc * NPAD + gi] = bits;
        } else {
            unsigned long long myword = 0ull;
            for (int j = 0; j < 64; ++j) {
                unsigned long long bal = __ballot((int)((bits >> j) & 1ull));
                if (lane == j) myword = bal;
            }
            maskT[(size_t)cc * NPAD + cc * 64 + lane] = myword;
        }
    }
}

// 6) greedy NMS: speculative ballot scan, split waves, early exit, compaction.
__global__ __launch_bounds__(1024) void k_nms(const unsigned long long* __restrict__ maskT,
                                              const float4* __restrict__ boxes,
                                              float4* __restrict__ out) {
    __shared__ unsigned long long removed[NCH];
    __shared__ unsigned long long aliveSh[2];
    __shared__ int cstop;
    __shared__ unsigned scanBuf[16];
    int t = threadIdx.x;
    int wave = t >> 6, lane = t & 63;

    if (t < NCH) removed[t] = (t == NCH - 1) ? 0xFFFF000000000000ull : 0ull;
    if (t == 0) cstop = -1;
    __syncthreads();

    unsigned long long colA = 0, wAr = 0, colB = 0, wBr = 0;  // wave0 regs
    unsigned long long mA[7], mB[7];                           // waves 1-15
    if (wave == 0) {
        colA = maskT[(size_t)0 * NPAD + 0 * 64 + lane];
        wAr = maskT[(size_t)1 * NPAD + 0 * 64 + lane];
        colB = maskT[(size_t)1 * NPAD + 1 * 64 + lane];
        wBr = maskT[(size_t)2 * NPAD + 1 * 64 + lane];
    } else {
#pragma unroll
        for (int q = 0; q < 7; ++q) {
            int w = 2 + (wave - 1) + 15 * q;
            mA[q] = (w < NCH) ? maskT[(size_t)w * NPAD + 0 * 64 + lane] : 0ull;
        }
#pragma unroll
        for (int q = 0; q < 7; ++q) {
            int w = 3 + (wave - 1) + 15 * q;
            mB[q] = (w < NCH) ? maskT[(size_t)w * NPAD + 1 * 64 + lane] : 0ull;
        }
    }
    unsigned keptTot = 0;

    for (int c = 0; c < NCH; c += 2) {
        if (wave == 0) {
            unsigned long long rem = removed[c];
            unsigned alo = __builtin_amdgcn_readfirstlane((unsigned)(~rem));
            unsigned ahi = __builtin_amdgcn_readfirstlane((unsigned)((~rem) >> 32));
            unsigned long long alive = ((unsigned long long)ahi << 32) | alo;
            alive = chunk_scan(colA, alive);
            keptTot += (unsigned)__popcll(alive);
            if (lane == 0) {
                removed[c] = ~alive;
                aliveSh[0] = alive;
                if (keptTot >= NOUT) cstop = c;
            }
            if (c + 1 < NCH) {
                unsigned long long sel = 0ull - ((alive >> lane) & 1ull);
                unsigned long long v = wAr & sel;
                unsigned lo = wave_or32((unsigned)v);
                unsigned hi = wave_or32((unsigned)(v >> 32));
                if (lane == 63) atomicOr(&removed[c + 1], ((unsigned long long)hi << 32) | lo);
            }
            if (c + 2 < NCH) {
                colA = maskT[(size_t)(c + 2) * NPAD + (c + 2) * 64 + lane];
                wAr = (c + 3 < NCH) ? maskT[(size_t)(c + 3) * NPAD + (c + 2) * 64 + lane] : 0ull;
            }
        }
        __syncthreads();  // B1
        if (cstop >= 0) break;
        if (wave > 0) {
            unsigned long long alive = aliveSh[0];
            unsigned long long sel = 0ull - ((alive >> lane) & 1ull);
#pragma unroll
            for (int q = 0; q < 7; ++q) {
                int w = c + 2 + (wave - 1) + 15 * q;
                if (w < NCH) {
                    unsigned long long v = mA[q] & sel;
                    unsigned lo = wave_or32((unsigned)v);
                    unsigned hi = wave_or32((unsigned)(v >> 32));
                    if (lane == 63) atomicOr(&removed[w], ((unsigned long long)hi << 32) | lo);
                }
            }
#pragma unroll
            for (int q = 0; q < 7; ++q) {
                int w = (c + 2) + 2 + (wave - 1) + 15 * q;
                mA[q] = (w < NCH) ? maskT[(size_t)w * NPAD + (c + 2) * 64 + lane] : 0ull;
            }
        }
        if (wave == 0) {
            unsigned long long rem = removed[c + 1];
            unsigned alo = __builtin_amdgcn_readfirstlane((unsigned)(~rem));
            unsigned ahi = __builtin_amdgcn_readfirstlane((unsigned)((~rem) >> 32));
            unsigned long long alive = ((unsigned long long)ahi << 32) | alo;
            alive = chunk_scan(colB, alive);
            keptTot += (unsigned)__popcll(alive);
            if (lane == 0) {
                removed[c + 1] = ~alive;
                aliveSh[1] = alive;
                if (keptTot >= NOUT) cstop = c + 1;
            }
            if (c + 2 < NCH) {
                unsigned long long sel = 0ull - ((alive >> lane) & 1ull);
                unsigned long long v = wBr & sel;
                unsigned lo = wave_or32((unsigned)v);
                unsigned hi = wave_or32((unsigned)(v >> 32));
                if (lane == 63) atomicOr(&removed[c + 2], ((unsigned long long)hi << 32) | lo);
            }
            if (c + 3 < NCH) {
                colB = maskT[(size_t)(c + 3) * NPAD + (c + 3) * 64 + lane];
                wBr = (c + 4 < NCH) ? maskT[(size_t)(c + 4) * NPAD + (c + 3) * 64 + lane] : 0ull;
            }
        }
        __syncthreads();  // B2
        if (cstop >= 0) break;
        if (wave > 0) {
            unsigned long long alive = aliveSh[1];
            unsigned long long sel = 0ull - ((alive >> lane) & 1ull);
#pragma unroll
            for (int q = 0; q < 7; ++q) {
                int w = c + 3 + (wave - 1) + 15 * q;
                if (w < NCH) {
                    unsigned long long v = mB[q] & sel;
                    unsigned lo = wave_or32((unsigned)v);
                    unsigned hi = wave_or32((unsigned)(v >> 32));
                    if (lane == 63) atomicOr(&removed[w], ((unsigned long long)hi << 32) | lo);
                }
            }
#pragma unroll
            for (int q = 0; q < 7; ++q) {
                int w = (c + 3) + 2 + (wave - 1) + 15 * q;
                mB[q] = (w < NCH) ? maskT[(size_t)w * NPAD + (c + 3) * 64 + lane] : 0ull;
            }
        }
    }
    __syncthreads();

    // stable compaction: kept (index asc) then suppressed (index asc), first 1000.
    // (1-barrier hierarchical scan: shfl-up within wave, 16 wave totals in LDS)
    int base = t * 6;
    unsigned cnt = 0, keepbits = 0;
    for (int q = 0; q < 6; ++q) {
        int i = base + q;
        if (i < NSEL) {
            bool kp = !((removed[i >> 6] >> (i & 63)) & 1ull);
            if (kp) { cnt++; keepbits |= (1u << q); }
        }
    }
    unsigned v = cnt;
#pragma unroll
    for (int off = 1; off < 64; off <<= 1) {
        unsigned u = (unsigned)__shfl_up((int)v, off, 64);
        if (lane >= off) v += u;
    }
    if (lane == 63) scanBuf[wave] = v;
    __syncthreads();
    unsigned waveOff = 0, NK = 0;
#pragma unroll
    for (int ww = 0; ww < 16; ++ww) {
        unsigned wv = scanBuf[ww];
        if (ww < wave) waveOff += wv;
        NK += wv;
    }
    unsigned incl = waveOff + v;
    unsigned kpos = incl - cnt;
    for (int q = 0; q < 6; ++q) {
        int i = base + q;
        if (i < NSEL) {
            bool kp = (keepbits >> q) & 1u;
            unsigned pos = kp ? kpos : (NK + (unsigned)i - kpos);
            if (kp) kpos++;
            if (pos < NOUT) out[pos] = boxes[i];
        }
    }
}

extern "C" void kernel_launch(void* const* d_in, const int* in_sizes, int n_in,
                              void* d_out, int out_size, void* d_ws, size_t ws_size,
                              hipStream_t stream) {
    const float* scores = (const float*)d_in[0];
    const float* bbox = (const float*)d_in[1];
    const float* im_info = (const float*)d_in[2];
    char* ws = (char*)d_ws;

    unsigned* hist = (unsigned*)(ws + WS_HIST);
    unsigned* binB = (unsigned*)(ws + WS_BINB);
    unsigned* nact = (unsigned*)(ws + WS_NACT);
    unsigned* activeList = (unsigned*)(ws + WS_ACTIVE);
    unsigned* binBase = (unsigned*)(ws + WS_BINBASE);
    unsigned long long* selKeys = (unsigned long long*)(ws + WS_SELKEYS);
    float4* boxes = (float4*)(ws + WS_BOXES);
    unsigned long long* maskT = (unsigned long long*)(ws + WS_MASK);
    float4* out = (float4*)d_out;

    hipMemsetAsync(ws, 0, WS_ZERO_BYTES, stream);

    k_hist<<<(KK / 4 + 255) / 256, 256, 0, stream>>>(scores, hist);
    k_findbin<<<1, 1024, 0, stream>>>(hist, binB, binBase, activeList, nact);
    k_gather<<<(KK / 4 + 255) / 256, 256, 0, stream>>>(scores, binB, binBase, selKeys);
    k_binsort<<<64, 256, 0, stream>>>(hist, binBase, activeList, nact, selKeys, bbox, im_info, boxes);
    k_mask<<<MASK_BLOCKS, 256, 0, stream>>>(boxes, maskT);
    k_nms<<<1, 1024, 0, stream>>>(maskT, boxes, out);
}